// Round 4
// baseline (413.246 us; speedup 1.0000x reference)
//
#include <hip/hip_runtime.h>
#include <math.h>

#define NN 3072
#define PP 4
#define INF_ 256
#define FF 64
#define LEAK 0.2f
#define KB2 384            // k2 blocks per p (8 rows each)
#define KS 4               // k4 K-split factor
#define KCH (NN / KS)      // 768 K per chunk
#define PNF (PP * NN * FF) // 786432

// workspace layout (float offsets)
#define WH1_OFF  0                         // 3072
#define WH2_OFF  (WH1_OFF + NN)
#define RS_OFF   (WH2_OFF + NN)            // P*N
#define CS_OFF   (RS_OFF + PP * NN)        // P*N
#define U_OFF    (CS_OFF + PP * NN)        // P*N
#define V_OFF    (U_OFF + PP * NN)         // P*N
#define SCAL_OFF (V_OFF + PP * NN)         // 4 (+pad)
#define WHT_OFF  (SCAL_OFF + 8)            // bf16 WhT [F][N]: N*F/2 floats
#define CP_OFF   (WHT_OFF + (NN * FF) / 2) // col partials P*KB2*N floats (18.9MB);
                                           // reused by k4 as partial buffer (12.6MB)

typedef short short8 __attribute__((ext_vector_type(8)));
typedef float floatx4 __attribute__((ext_vector_type(4)));

__device__ inline unsigned short f2bf(float x) {
    unsigned u = __float_as_uint(x);
    return (unsigned short)((u + 0x7FFFu + ((u >> 16) & 1u)) >> 16);
}

// K1: Wh = h@W; store WhT bf16 [f][row]; Wh1 = Wh@a[:64]; Wh2 = Wh@a[64:]
__global__ __launch_bounds__(64) void k1_gemm(const float* __restrict__ h,
                                              const float* __restrict__ W,
                                              const float* __restrict__ a,
                                              float* __restrict__ ws) {
    int row = blockIdx.x;
    int f = threadIdx.x;
    __shared__ float hrow[INF_];
    ((float4*)hrow)[f] = ((const float4*)(h + (size_t)row * INF_))[f];
    __syncthreads();
    float acc = 0.f;
#pragma unroll 8
    for (int k = 0; k < INF_; ++k) acc = fmaf(hrow[k], W[k * FF + f], acc);
    unsigned short* whT = (unsigned short*)(ws + WHT_OFF);
    whT[(size_t)f * NN + row] = f2bf(acc);
    float s1 = acc * a[f];
    float s2 = acc * a[FF + f];
#pragma unroll
    for (int off = 32; off > 0; off >>= 1) {
        s1 += __shfl_down(s1, off);
        s2 += __shfl_down(s2, off);
    }
    if (f == 0) { ws[WH1_OFF + row] = s1; ws[WH2_OFF + row] = s2; }
}

// K2: e = leaky(Wh1[i]+Wh2[j])*edge; write e (nontemporal); row sums direct;
// col partials. 8 rows x 3072 cols per block. Grid (384, P) = 1536 blocks.
__global__ __launch_bounds__(256) void k2_e(const float* __restrict__ edge,
                                            float* __restrict__ e_out,
                                            float* __restrict__ ws) {
    int p = blockIdx.y;
    int row0 = blockIdx.x * 8;
    int tid = threadIdx.x;
    const float* Wh1 = ws + WH1_OFF;
    const float4* Wh2v = (const float4*)(ws + WH2_OFF);
    float4 wv[3];
#pragma unroll
    for (int c = 0; c < 3; ++c) wv[c] = Wh2v[c * 256 + tid];
    float colAcc[12];
#pragma unroll
    for (int i = 0; i < 12; ++i) colAcc[i] = 0.f;
    __shared__ float rowpart[8][4];
    const size_t slice = (size_t)p * NN * NN;
#pragma unroll 2
    for (int r = 0; r < 8; ++r) {
        int row = row0 + r;
        float w1 = Wh1[row];
        const float4* ein = (const float4*)(edge + slice + (size_t)row * NN);
        float* eoutf = e_out + slice + (size_t)row * NN;
        float racc = 0.f;
#pragma unroll
        for (int c = 0; c < 3; ++c) {
            int j4 = c * 256 + tid;
            float4 ea = ein[j4];
            float4 w = wv[c];
            floatx4 ev;
            float b;
            b = w1 + w.x; b = b > 0.f ? b : LEAK * b; ev.x = b * ea.x;
            b = w1 + w.y; b = b > 0.f ? b : LEAK * b; ev.y = b * ea.y;
            b = w1 + w.z; b = b > 0.f ? b : LEAK * b; ev.z = b * ea.z;
            b = w1 + w.w; b = b > 0.f ? b : LEAK * b; ev.w = b * ea.w;
            // nontemporal: ext-vector type required by the builtin
            __builtin_nontemporal_store(ev, (floatx4*)(eoutf + (size_t)j4 * 4));
            colAcc[c * 4 + 0] += ev.x; colAcc[c * 4 + 1] += ev.y;
            colAcc[c * 4 + 2] += ev.z; colAcc[c * 4 + 3] += ev.w;
            racc += (ev.x + ev.y) + (ev.z + ev.w);
        }
#pragma unroll
        for (int off = 32; off > 0; off >>= 1) racc += __shfl_down(racc, off);
        if ((tid & 63) == 0) rowpart[r][tid >> 6] = racc;
    }
    __syncthreads();
    if (tid < 32) {
        float vv = rowpart[tid >> 2][tid & 3];
        vv += __shfl_down(vv, 2);
        vv += __shfl_down(vv, 1);
        if ((tid & 3) == 0) ws[RS_OFF + p * NN + row0 + (tid >> 2)] = vv;
    }
    float4* cp = (float4*)(ws + CP_OFF + (size_t)(p * KB2 + blockIdx.x) * NN);
#pragma unroll
    for (int c = 0; c < 3; ++c) {
        float4 cv;
        cv.x = colAcc[c * 4 + 0]; cv.y = colAcc[c * 4 + 1];
        cv.z = colAcc[c * 4 + 2]; cv.w = colAcc[c * 4 + 3];
        cp[c * 256 + tid] = cv;
    }
}

// K3a: reduce 384 col partials -> cs. Grid (48, P); 256 thr = 64 cols x 4 chunks.
__global__ __launch_bounds__(256) void k3a_red(float* __restrict__ ws) {
    int p = blockIdx.y;
    int col = blockIdx.x * 64 + (threadIdx.x & 63);
    int chunk = threadIdx.x >> 6;  // 0..3, 96 partials each
    const float* cp = ws + CP_OFF + (size_t)p * KB2 * NN + (size_t)chunk * 96 * NN + col;
    float s = 0.f;
#pragma unroll 8
    for (int b = 0; b < 96; ++b) s += cp[(size_t)b * NN];
    __shared__ float sred[4][64];
    sred[chunk][threadIdx.x & 63] = s;
    __syncthreads();
    if (threadIdx.x < 64) {
        float t = sred[0][threadIdx.x] + sred[1][threadIdx.x] +
                  sred[2][threadIdx.x] + sred[3][threadIdx.x];
        ws[CS_OFF + p * NN + col] = t;
    }
}

// K3b: per-p scalars. lamb = max(max rs, max cs); r = N*lamb - T.
// Analytic: tt col-0 sum == lamb => denom = lamb.
// u_i = (lamb-rs_i)/(r*lamb); v_j = lamb-cs_j; att = e>0 ? e/lamb + u_i*v_j : e
__global__ __launch_bounds__(256) void k3b_scal(float* __restrict__ ws) {
    int p = blockIdx.x;
    int tid = threadIdx.x;
    const float* rs = ws + RS_OFF + p * NN;
    const float* cs = ws + CS_OFF + p * NN;
    float mx = -3.4e38f, sum = 0.f;
    for (int i = tid; i < NN; i += 256) {
        float rv = rs[i], cv = cs[i];
        mx = fmaxf(mx, fmaxf(rv, cv));
        sum += rv;
    }
#pragma unroll
    for (int off = 32; off > 0; off >>= 1) {
        mx = fmaxf(mx, __shfl_down(mx, off));
        sum += __shfl_down(sum, off);
    }
    __shared__ float smx[4], ssum[4];
    __shared__ float s_lamb, s_invlr;
    if ((tid & 63) == 0) { smx[tid >> 6] = mx; ssum[tid >> 6] = sum; }
    __syncthreads();
    if (tid == 0) {
        float lamb = fmaxf(fmaxf(smx[0], smx[1]), fmaxf(smx[2], smx[3]));
        float T = ssum[0] + ssum[1] + ssum[2] + ssum[3];
        float r = (float)NN * lamb - T;
        s_lamb = lamb;
        s_invlr = 1.f / (r * lamb);
        ws[SCAL_OFF + p] = 1.f / lamb;
    }
    __syncthreads();
    float lamb = s_lamb, invlr = s_invlr;
    for (int i = tid; i < NN; i += 256) {
        ws[U_OFF + p * NN + i] = (lamb - rs[i]) * invlr;
        ws[V_OFF + p * NN + i] = lamb - cs[i];
    }
}

// K4: partial h_prime = att(e[:, Kchunk]) @ Wh[Kchunk, :] via bf16 MFMA.
// Barrier-free, LDS-free: each lane loads/transforms exactly its own MFMA
// fragments in registers.
//   A frag (16x16x32): lane holds A[row = lane&15][k = (lane>>4)*8 + 0..7]
//   B frag: lane holds whT[f = nt*16 + (lane&15)][k0 + (lane>>4)*8 + 0..7]
// Grid (192, P, KS) = 3072 single-wave blocks -> 12 waves/CU.
// Partial [16x64] f32 per block into ws (cp region reused), layout [z][p][n][f].
__global__ __launch_bounds__(64) void k4_mfma(const float* __restrict__ e_in,
                                              float* __restrict__ ws) {
    int p = blockIdx.y;
    int z = blockIdx.z;
    int row0 = blockIdx.x * 16;
    int tid = threadIdx.x;
    const unsigned short* whT = (const unsigned short*)(ws + WHT_OFF);
    const float* u = ws + U_OFF + p * NN;
    const float* v = ws + V_OFF + p * NN;
    float invl = ws[SCAL_OFF + p];
    const float* eslice = e_in + (size_t)p * NN * NN;

    const int mrow = tid & 15;   // A row / B col this lane owns
    const int kq = tid >> 4;     // k-octet 0..3: k = kq*8 .. kq*8+7
    float u_r = u[row0 + mrow];
    const float4* erow = (const float4*)(eslice + (size_t)(row0 + mrow) * NN);
    const float4* vrow = (const float4*)v;
    const short8* w0 = (const short8*)(whT + (size_t)(0 * 16 + mrow) * NN);
    const short8* w1 = (const short8*)(whT + (size_t)(1 * 16 + mrow) * NN);
    const short8* w2 = (const short8*)(whT + (size_t)(2 * 16 + mrow) * NN);
    const short8* w3 = (const short8*)(whT + (size_t)(3 * 16 + mrow) * NN);

    floatx4 acc[4];
#pragma unroll
    for (int nt = 0; nt < 4; ++nt)
#pragma unroll
        for (int i = 0; i < 4; ++i) acc[nt][i] = 0.f;

    const int kbase = z * KCH;
#pragma unroll 2
    for (int k0 = kbase; k0 < kbase + KCH; k0 += 32) {
        int ei = (k0 >> 2) + (kq << 1);     // float4 idx: floats k0 + kq*8
        float4 e0 = erow[ei];
        float4 e1 = erow[ei + 1];
        float4 v0 = vrow[ei];
        float4 v1 = vrow[ei + 1];
        int wi = (k0 >> 3) + kq;            // short8 idx: shorts k0 + kq*8
        short8 b0 = w0[wi];
        short8 b1 = w1[wi];
        short8 b2 = w2[wi];
        short8 b3 = w3[wi];
        float a0 = e0.x > 0.f ? fmaf(u_r, v0.x, e0.x * invl) : e0.x;
        float a1 = e0.y > 0.f ? fmaf(u_r, v0.y, e0.y * invl) : e0.y;
        float a2 = e0.z > 0.f ? fmaf(u_r, v0.z, e0.z * invl) : e0.z;
        float a3 = e0.w > 0.f ? fmaf(u_r, v0.w, e0.w * invl) : e0.w;
        float a4 = e1.x > 0.f ? fmaf(u_r, v1.x, e1.x * invl) : e1.x;
        float a5 = e1.y > 0.f ? fmaf(u_r, v1.y, e1.y * invl) : e1.y;
        float a6 = e1.z > 0.f ? fmaf(u_r, v1.z, e1.z * invl) : e1.z;
        float a7 = e1.w > 0.f ? fmaf(u_r, v1.w, e1.w * invl) : e1.w;
        int4 pa;
        pa.x = (int)f2bf(a0) | ((int)f2bf(a1) << 16);
        pa.y = (int)f2bf(a2) | ((int)f2bf(a3) << 16);
        pa.z = (int)f2bf(a4) | ((int)f2bf(a5) << 16);
        pa.w = (int)f2bf(a6) | ((int)f2bf(a7) << 16);
        short8 af = *(short8*)&pa;
        acc[0] = __builtin_amdgcn_mfma_f32_16x16x32_bf16(af, b0, acc[0], 0, 0, 0);
        acc[1] = __builtin_amdgcn_mfma_f32_16x16x32_bf16(af, b1, acc[1], 0, 0, 0);
        acc[2] = __builtin_amdgcn_mfma_f32_16x16x32_bf16(af, b2, acc[2], 0, 0, 0);
        acc[3] = __builtin_amdgcn_mfma_f32_16x16x32_bf16(af, b3, acc[3], 0, 0, 0);
    }
    // D layout: col = lane&15, row = (lane>>4)*4 + reg  [m89-verified]
    float* part = ws + CP_OFF + (size_t)z * PNF + (size_t)p * NN * FF + (size_t)row0 * FF;
#pragma unroll
    for (int nt = 0; nt < 4; ++nt)
#pragma unroll
        for (int r = 0; r < 4; ++r)
            part[((tid >> 4) * 4 + r) * FF + nt * 16 + (tid & 15)] = acc[nt][r];
}

// K5: sum KS partials + elu -> out0[n, p*64+f]. Grid 3072 x 256.
__global__ __launch_bounds__(256) void k5_red(const float* __restrict__ ws,
                                              float* __restrict__ out0) {
    int i = blockIdx.x * 256 + threadIdx.x;  // over [p][n][f]
    const float* part = ws + CP_OFF;
    float s = part[i] + part[PNF + i] + part[2 * PNF + i] + part[3 * (size_t)PNF + i];
    s = s > 0.f ? s : (expf(s) - 1.0f);  // elu alpha=1
    int f = i & 63;
    int p = i / (NN * FF);
    int n = (i - p * NN * FF) >> 6;
    out0[(size_t)n * (PP * FF) + p * FF + f] = s;
}

extern "C" void kernel_launch(void* const* d_in, const int* in_sizes, int n_in,
                              void* d_out, int out_size, void* d_ws, size_t ws_size,
                              hipStream_t stream) {
    const float* h    = (const float*)d_in[0];
    const float* edge = (const float*)d_in[1];
    const float* W    = (const float*)d_in[2];
    const float* a    = (const float*)d_in[3];
    float* out0  = (float*)d_out;                // [N, P*F] elu output
    float* e_out = out0 + (size_t)NN * PP * FF;  // [P, N, N] e output
    float* ws = (float*)d_ws;

    k1_gemm<<<NN, 64, 0, stream>>>(h, W, a, ws);
    k2_e<<<dim3(NN / 8, PP), 256, 0, stream>>>(edge, e_out, ws);
    k3a_red<<<dim3(NN / 64, PP), 256, 0, stream>>>(ws);
    k3b_scal<<<PP, 256, 0, stream>>>(ws);
    k4_mfma<<<dim3(NN / 16, PP, KS), 64, 0, stream>>>(e_out, ws);
    k5_red<<<PNF / 256, 256, 0, stream>>>(ws, out0);
}

// Round 5
// 356.352 us; speedup vs baseline: 1.1597x; 1.1597x over previous
//
#include <hip/hip_runtime.h>
#include <math.h>

#define NN 3072
#define PP 4
#define INF_ 256
#define FF 64
#define LEAK 0.2f
#define KB2 384            // k2 blocks per p (8 rows each)
#define KS 4               // k4 K-split factor
#define KCH (NN / KS)      // 768 K per chunk
#define PNF (PP * NN * FF) // 786432

// workspace layout (float offsets)
#define WH1_OFF  0                         // 3072
#define WH2_OFF  (WH1_OFF + NN)
#define RS_OFF   (WH2_OFF + NN)            // P*N
#define CS_OFF   (RS_OFF + PP * NN)        // P*N
#define U_OFF    (CS_OFF + PP * NN)        // P*N
#define V_OFF    (U_OFF + PP * NN)         // P*N
#define SCAL_OFF (V_OFF + PP * NN)         // 4 (+pad)
#define WHT_OFF  (SCAL_OFF + 8)            // bf16 WhT [F][N]: N*F/2 floats
#define CP_OFF   (WHT_OFF + (NN * FF) / 2) // col partials P*KB2*N floats (18.9MB);
                                           // reused by k4 as partial buffer (12.6MB)

typedef short short8 __attribute__((ext_vector_type(8)));
typedef float floatx4 __attribute__((ext_vector_type(4)));

__device__ inline unsigned short f2bf(float x) {
    unsigned u = __float_as_uint(x);
    return (unsigned short)((u + 0x7FFFu + ((u >> 16) & 1u)) >> 16);
}

// K1: Wh = h@W; store WhT bf16 [f][row]; Wh1 = Wh@a[:64]; Wh2 = Wh@a[64:]
__global__ __launch_bounds__(64) void k1_gemm(const float* __restrict__ h,
                                              const float* __restrict__ W,
                                              const float* __restrict__ a,
                                              float* __restrict__ ws) {
    int row = blockIdx.x;
    int f = threadIdx.x;
    __shared__ float hrow[INF_];
    ((float4*)hrow)[f] = ((const float4*)(h + (size_t)row * INF_))[f];
    __syncthreads();
    float acc = 0.f;
#pragma unroll 8
    for (int k = 0; k < INF_; ++k) acc = fmaf(hrow[k], W[k * FF + f], acc);
    unsigned short* whT = (unsigned short*)(ws + WHT_OFF);
    whT[(size_t)f * NN + row] = f2bf(acc);
    float s1 = acc * a[f];
    float s2 = acc * a[FF + f];
#pragma unroll
    for (int off = 32; off > 0; off >>= 1) {
        s1 += __shfl_down(s1, off);
        s2 += __shfl_down(s2, off);
    }
    if (f == 0) { ws[WH1_OFF + row] = s1; ws[WH2_OFF + row] = s2; }
}

// K2: e = leaky(Wh1[i]+Wh2[j])*edge; write e; row sums DEFERRED to after the
// memory stream; next-row prefetch keeps loads in flight. 8 rows x 3072 cols
// per block. Grid (384, P) = 1536 blocks.
__global__ __launch_bounds__(256) void k2_e(const float* __restrict__ edge,
                                            float* __restrict__ e_out,
                                            float* __restrict__ ws) {
    int p = blockIdx.y;
    int row0 = blockIdx.x * 8;
    int tid = threadIdx.x;
    const float* Wh1 = ws + WH1_OFF;
    const float4* Wh2v = (const float4*)(ws + WH2_OFF);
    float4 wv[3];
#pragma unroll
    for (int c = 0; c < 3; ++c) wv[c] = Wh2v[c * 256 + tid];
    float colAcc[12];
#pragma unroll
    for (int i = 0; i < 12; ++i) colAcc[i] = 0.f;
    float racc8[8];
    __shared__ float rowpart[8][4];
    const size_t slice = (size_t)p * NN * NN;
    const float4* ein = (const float4*)(edge + slice + (size_t)row0 * NN);
    float4* eout = (float4*)(e_out + slice + (size_t)row0 * NN);
    // row stride = NN/4 = 768 float4
    float4 c0 = ein[tid], c1 = ein[256 + tid], c2 = ein[512 + tid];
#pragma unroll
    for (int r = 0; r < 8; ++r) {
        float4 n0, n1, n2;
        if (r < 7) {
            const float4* nx = ein + (size_t)(r + 1) * 768;
            n0 = nx[tid]; n1 = nx[256 + tid]; n2 = nx[512 + tid];
        }
        float w1 = Wh1[row0 + r];
        float4* eor = eout + (size_t)r * 768;
        float racc = 0.f;
        float4 ea, w, ev;
        float b;
        // c = 0
        ea = c0; w = wv[0];
        b = w1 + w.x; b = b > 0.f ? b : LEAK * b; ev.x = b * ea.x;
        b = w1 + w.y; b = b > 0.f ? b : LEAK * b; ev.y = b * ea.y;
        b = w1 + w.z; b = b > 0.f ? b : LEAK * b; ev.z = b * ea.z;
        b = w1 + w.w; b = b > 0.f ? b : LEAK * b; ev.w = b * ea.w;
        eor[tid] = ev;
        colAcc[0] += ev.x; colAcc[1] += ev.y; colAcc[2] += ev.z; colAcc[3] += ev.w;
        racc += (ev.x + ev.y) + (ev.z + ev.w);
        // c = 1
        ea = c1; w = wv[1];
        b = w1 + w.x; b = b > 0.f ? b : LEAK * b; ev.x = b * ea.x;
        b = w1 + w.y; b = b > 0.f ? b : LEAK * b; ev.y = b * ea.y;
        b = w1 + w.z; b = b > 0.f ? b : LEAK * b; ev.z = b * ea.z;
        b = w1 + w.w; b = b > 0.f ? b : LEAK * b; ev.w = b * ea.w;
        eor[256 + tid] = ev;
        colAcc[4] += ev.x; colAcc[5] += ev.y; colAcc[6] += ev.z; colAcc[7] += ev.w;
        racc += (ev.x + ev.y) + (ev.z + ev.w);
        // c = 2
        ea = c2; w = wv[2];
        b = w1 + w.x; b = b > 0.f ? b : LEAK * b; ev.x = b * ea.x;
        b = w1 + w.y; b = b > 0.f ? b : LEAK * b; ev.y = b * ea.y;
        b = w1 + w.z; b = b > 0.f ? b : LEAK * b; ev.z = b * ea.z;
        b = w1 + w.w; b = b > 0.f ? b : LEAK * b; ev.w = b * ea.w;
        eor[512 + tid] = ev;
        colAcc[8] += ev.x; colAcc[9] += ev.y; colAcc[10] += ev.z; colAcc[11] += ev.w;
        racc += (ev.x + ev.y) + (ev.z + ev.w);
        racc8[r] = racc;
        c0 = n0; c1 = n1; c2 = n2;
    }
    // deferred row reductions
#pragma unroll
    for (int r = 0; r < 8; ++r) {
        float racc = racc8[r];
#pragma unroll
        for (int off = 32; off > 0; off >>= 1) racc += __shfl_down(racc, off);
        if ((tid & 63) == 0) rowpart[r][tid >> 6] = racc;
    }
    __syncthreads();
    if (tid < 32) {
        float vv = rowpart[tid >> 2][tid & 3];
        vv += __shfl_down(vv, 2);
        vv += __shfl_down(vv, 1);
        if ((tid & 3) == 0) ws[RS_OFF + p * NN + row0 + (tid >> 2)] = vv;
    }
    float4* cp = (float4*)(ws + CP_OFF + (size_t)(p * KB2 + blockIdx.x) * NN);
#pragma unroll
    for (int c = 0; c < 3; ++c) {
        float4 cv;
        cv.x = colAcc[c * 4 + 0]; cv.y = colAcc[c * 4 + 1];
        cv.z = colAcc[c * 4 + 2]; cv.w = colAcc[c * 4 + 3];
        cp[c * 256 + tid] = cv;
    }
}

// K3a: reduce 384 col partials -> cs. Grid (48, P); 256 thr = 64 cols x 4 chunks.
__global__ __launch_bounds__(256) void k3a_red(float* __restrict__ ws) {
    int p = blockIdx.y;
    int col = blockIdx.x * 64 + (threadIdx.x & 63);
    int chunk = threadIdx.x >> 6;  // 0..3, 96 partials each
    const float* cp = ws + CP_OFF + (size_t)p * KB2 * NN + (size_t)chunk * 96 * NN + col;
    float s = 0.f;
#pragma unroll 8
    for (int b = 0; b < 96; ++b) s += cp[(size_t)b * NN];
    __shared__ float sred[4][64];
    sred[chunk][threadIdx.x & 63] = s;
    __syncthreads();
    if (threadIdx.x < 64) {
        float t = sred[0][threadIdx.x] + sred[1][threadIdx.x] +
                  sred[2][threadIdx.x] + sred[3][threadIdx.x];
        ws[CS_OFF + p * NN + col] = t;
    }
}

// K3b: per-p scalars. lamb = max(max rs, max cs); r = N*lamb - T.
// u_i = (lamb-rs_i)/(r*lamb); v_j = lamb-cs_j; att = e>0 ? e/lamb + u_i*v_j : e
__global__ __launch_bounds__(256) void k3b_scal(float* __restrict__ ws) {
    int p = blockIdx.x;
    int tid = threadIdx.x;
    const float* rs = ws + RS_OFF + p * NN;
    const float* cs = ws + CS_OFF + p * NN;
    float mx = -3.4e38f, sum = 0.f;
    for (int i = tid; i < NN; i += 256) {
        float rv = rs[i], cv = cs[i];
        mx = fmaxf(mx, fmaxf(rv, cv));
        sum += rv;
    }
#pragma unroll
    for (int off = 32; off > 0; off >>= 1) {
        mx = fmaxf(mx, __shfl_down(mx, off));
        sum += __shfl_down(sum, off);
    }
    __shared__ float smx[4], ssum[4];
    __shared__ float s_lamb, s_invlr;
    if ((tid & 63) == 0) { smx[tid >> 6] = mx; ssum[tid >> 6] = sum; }
    __syncthreads();
    if (tid == 0) {
        float lamb = fmaxf(fmaxf(smx[0], smx[1]), fmaxf(smx[2], smx[3]));
        float T = ssum[0] + ssum[1] + ssum[2] + ssum[3];
        float r = (float)NN * lamb - T;
        s_lamb = lamb;
        s_invlr = 1.f / (r * lamb);
        ws[SCAL_OFF + p] = 1.f / lamb;
    }
    __syncthreads();
    float lamb = s_lamb, invlr = s_invlr;
    for (int i = tid; i < NN; i += 256) {
        ws[U_OFF + p * NN + i] = (lamb - rs[i]) * invlr;
        ws[V_OFF + p * NN + i] = lamb - cs[i];
    }
}

// K4: partial h_prime = att(e[:, Kchunk]) @ Wh[Kchunk, :] via bf16 MFMA.
// 256-thread (4-wave) blocks, 32x64 C-tile, COALESCED cooperative staging of
// the e-tile (transform applied during staging) + whT tile into XOR-swizzled
// LDS (slot ^= row&7 -> conflict-free b128 frag reads), double-buffered,
// 1 barrier per 64-K step. Grid (96, P, KS) = 1536 blocks -> 24 waves/CU.
__global__ __launch_bounds__(256) void k4_mfma(const float* __restrict__ e_in,
                                               float* __restrict__ ws) {
    int p = blockIdx.y;
    int z = blockIdx.z;
    int row0 = blockIdx.x * 32;
    int tid = threadIdx.x;
    int lane = tid & 63, wid = tid >> 6;

    __shared__ unsigned short sA[2][32 * 64];  // bf16 A-tile, swizzled
    __shared__ unsigned short sB[2][64 * 64];  // bf16 B-tile (whT), swizzled

    const unsigned short* whT = (const unsigned short*)(ws + WHT_OFF);
    const float* u = ws + U_OFF + p * NN;
    const float* v = ws + V_OFF + p * NN;
    float invl = ws[SCAL_OFF + p];
    const float* eslice = e_in + (size_t)p * NN * NN;

    // staging roles
    const int ar = tid >> 3, acg = tid & 7;   // A: row 0..31, col-group (4 floats; halves at +0/+32)
    const int bfr = tid >> 2, bkg = tid & 3;  // B: f-row 0..63, k-group (8 shorts; second at +32)
    const float u_r = u[row0 + ar];
    const float* erow = eslice + (size_t)(row0 + ar) * NN;
    const unsigned short* wrow = whT + (size_t)bfr * NN;
    const int aswL = ((acg >> 1) ^ (ar & 7)) * 8 + (acg & 1) * 4;
    const int aswH = (((acg >> 1) + 4) ^ (ar & 7)) * 8 + (acg & 1) * 4;
    const int bswL = (bkg ^ (bfr & 7)) * 8;
    const int bswH = ((bkg + 4) ^ (bfr & 7)) * 8;

    // fragment roles
    const int mrow = lane & 15, kq = lane >> 4;
    const int rt = wid & 1, ft = (wid >> 1) * 2;  // row-tile, first f-tile
    const int arow = rt * 16 + mrow;
    const int sw = mrow & 7;

    floatx4 acc0, acc1;
#pragma unroll
    for (int i = 0; i < 4; ++i) { acc0[i] = 0.f; acc1[i] = 0.f; }

    float4 eL, eH, vL, vH;
    int4 bLd, bHd;
    auto LD = [&](int k0) {
        const float4* ep = (const float4*)(erow + k0);
        eL = ep[acg]; eH = ep[acg + 8];
        const float4* vp = (const float4*)(v + k0);
        vL = vp[acg]; vH = vp[acg + 8];
        const int4* wp = (const int4*)(wrow + k0);
        bLd = wp[bkg]; bHd = wp[bkg + 4];
    };
    auto ST = [&](int b) {
        float a0 = eL.x > 0.f ? fmaf(u_r, vL.x, eL.x * invl) : eL.x;
        float a1 = eL.y > 0.f ? fmaf(u_r, vL.y, eL.y * invl) : eL.y;
        float a2 = eL.z > 0.f ? fmaf(u_r, vL.z, eL.z * invl) : eL.z;
        float a3 = eL.w > 0.f ? fmaf(u_r, vL.w, eL.w * invl) : eL.w;
        float a4 = eH.x > 0.f ? fmaf(u_r, vH.x, eH.x * invl) : eH.x;
        float a5 = eH.y > 0.f ? fmaf(u_r, vH.y, eH.y * invl) : eH.y;
        float a6 = eH.z > 0.f ? fmaf(u_r, vH.z, eH.z * invl) : eH.z;
        float a7 = eH.w > 0.f ? fmaf(u_r, vH.w, eH.w * invl) : eH.w;
        int2 lo, hi;
        lo.x = (int)f2bf(a0) | ((int)f2bf(a1) << 16);
        lo.y = (int)f2bf(a2) | ((int)f2bf(a3) << 16);
        hi.x = (int)f2bf(a4) | ((int)f2bf(a5) << 16);
        hi.y = (int)f2bf(a6) | ((int)f2bf(a7) << 16);
        *(int2*)&sA[b][ar * 64 + aswL] = lo;
        *(int2*)&sA[b][ar * 64 + aswH] = hi;
        *(int4*)&sB[b][bfr * 64 + bswL] = bLd;
        *(int4*)&sB[b][bfr * 64 + bswH] = bHd;
    };
    auto MM = [&](int b) {
        short8 a0 = *(const short8*)&sA[b][arow * 64 + (kq ^ sw) * 8];
        short8 a1 = *(const short8*)&sA[b][arow * 64 + ((4 + kq) ^ sw) * 8];
        int f0 = (ft * 16 + mrow) * 64;
        int f1 = f0 + 16 * 64;
        short8 b00 = *(const short8*)&sB[b][f0 + (kq ^ sw) * 8];
        short8 b01 = *(const short8*)&sB[b][f0 + ((4 + kq) ^ sw) * 8];
        short8 b10 = *(const short8*)&sB[b][f1 + (kq ^ sw) * 8];
        short8 b11 = *(const short8*)&sB[b][f1 + ((4 + kq) ^ sw) * 8];
        acc0 = __builtin_amdgcn_mfma_f32_16x16x32_bf16(a0, b00, acc0, 0, 0, 0);
        acc0 = __builtin_amdgcn_mfma_f32_16x16x32_bf16(a1, b01, acc0, 0, 0, 0);
        acc1 = __builtin_amdgcn_mfma_f32_16x16x32_bf16(a0, b10, acc1, 0, 0, 0);
        acc1 = __builtin_amdgcn_mfma_f32_16x16x32_bf16(a1, b11, acc1, 0, 0, 0);
    };

    const int kbase = z * KCH;
    const int NSTEP = KCH / 64;  // 12
    LD(kbase);
    ST(0);
    __syncthreads();
    int buf = 0;
    for (int step = 0; step < NSTEP; ++step) {
        if (step + 1 < NSTEP) {
            LD(kbase + (step + 1) * 64);   // issue next-tile global loads
            MM(buf);                        // compute current (independent)
            ST(buf ^ 1);                    // waits on loads, writes other buffer
            __syncthreads();
        } else {
            MM(buf);
        }
        buf ^= 1;
    }
    // D layout: col = lane&15, row = (lane>>4)*4 + reg  [m89-verified]
    float* part = ws + CP_OFF + (size_t)z * PNF + (size_t)p * NN * FF + (size_t)row0 * FF;
#pragma unroll
    for (int r = 0; r < 4; ++r) {
        int crow = rt * 16 + kq * 4 + r;
        part[crow * FF + ft * 16 + mrow] = acc0[r];
        part[crow * FF + (ft + 1) * 16 + mrow] = acc1[r];
    }
}

// K5: sum KS partials + elu -> out0[n, p*64+f]. Grid 3072 x 256.
__global__ __launch_bounds__(256) void k5_red(const float* __restrict__ ws,
                                              float* __restrict__ out0) {
    int i = blockIdx.x * 256 + threadIdx.x;  // over [p][n][f]
    const float* part = ws + CP_OFF;
    float s = part[i] + part[PNF + i] + part[2 * PNF + i] + part[3 * (size_t)PNF + i];
    s = s > 0.f ? s : (expf(s) - 1.0f);  // elu alpha=1
    int f = i & 63;
    int p = i / (NN * FF);
    int n = (i - p * NN * FF) >> 6;
    out0[(size_t)n * (PP * FF) + p * FF + f] = s;
}

extern "C" void kernel_launch(void* const* d_in, const int* in_sizes, int n_in,
                              void* d_out, int out_size, void* d_ws, size_t ws_size,
                              hipStream_t stream) {
    const float* h    = (const float*)d_in[0];
    const float* edge = (const float*)d_in[1];
    const float* W    = (const float*)d_in[2];
    const float* a    = (const float*)d_in[3];
    float* out0  = (float*)d_out;                // [N, P*F] elu output
    float* e_out = out0 + (size_t)NN * PP * FF;  // [P, N, N] e output
    float* ws = (float*)d_ws;

    k1_gemm<<<NN, 64, 0, stream>>>(h, W, a, ws);
    k2_e<<<dim3(NN / 8, PP), 256, 0, stream>>>(edge, e_out, ws);
    k3a_red<<<dim3(NN / 64, PP), 256, 0, stream>>>(ws);
    k3b_scal<<<PP, 256, 0, stream>>>(ws);
    k4_mfma<<<dim3(NN / 32, PP, KS), 256, 0, stream>>>(e_out, ws);
    k5_red<<<PNF / 256, 256, 0, stream>>>(ws, out0);
}

// Round 8
// 340.157 us; speedup vs baseline: 1.2149x; 1.0476x over previous
//
#include <hip/hip_runtime.h>
#include <math.h>

#define NN 3072
#define PP 4
#define INF_ 256
#define FF 64
#define LEAK 0.2f
#define KB2 192            // k2 blocks per p (16 rows each)
#define KS 4               // k4 K-split factor
#define KCH (NN / KS)      // 768 K per chunk
#define PNF (PP * NN * FF) // 786432

// workspace layout (float offsets)
#define WH1_OFF  0                         // 3072
#define WH2_OFF  (WH1_OFF + NN)
#define RS_OFF   (WH2_OFF + NN)            // P*N
#define CS_OFF   (RS_OFF + PP * NN)        // P*N
#define U_OFF    (CS_OFF + PP * NN)        // P*N
#define V_OFF    (U_OFF + PP * NN)         // P*N
#define SCAL_OFF (V_OFF + PP * NN)         // 4 (+pad)
#define WHT_OFF  (SCAL_OFF + 8)            // bf16 WhT [F][N]: N*F/2 floats
#define CP_OFF   (WHT_OFF + (NN * FF) / 2) // col partials P*KB2*N floats (9.4MB);
                                           // reused by k4 as partial buffer (12.6MB)

typedef short short8 __attribute__((ext_vector_type(8)));
typedef float floatx4 __attribute__((ext_vector_type(4)));

__device__ inline unsigned short f2bf(float x) {
    unsigned u = __float_as_uint(x);
    return (unsigned short)((u + 0x7FFFu + ((u >> 16) & 1u)) >> 16);
}

// K1: Wh = h@W; store WhT bf16 [f][row]; Wh1 = Wh@a[:64]; Wh2 = Wh@a[64:]
__global__ __launch_bounds__(64) void k1_gemm(const float* __restrict__ h,
                                              const float* __restrict__ W,
                                              const float* __restrict__ a,
                                              float* __restrict__ ws) {
    int row = blockIdx.x;
    int f = threadIdx.x;
    __shared__ float hrow[INF_];
    ((float4*)hrow)[f] = ((const float4*)(h + (size_t)row * INF_))[f];
    __syncthreads();
    float acc = 0.f;
#pragma unroll 8
    for (int k = 0; k < INF_; ++k) acc = fmaf(hrow[k], W[k * FF + f], acc);
    unsigned short* whT = (unsigned short*)(ws + WHT_OFF);
    whT[(size_t)f * NN + row] = f2bf(acc);
    float s1 = acc * a[f];
    float s2 = acc * a[FF + f];
#pragma unroll
    for (int off = 32; off > 0; off >>= 1) {
        s1 += __shfl_down(s1, off);
        s2 += __shfl_down(s2, off);
    }
    if (f == 0) { ws[WH1_OFF + row] = s1; ws[WH2_OFF + row] = s2; }
}

// K2: e = leaky(Wh1[i]+Wh2[j])*edge; write e; row sums deferred; next-row
// prefetch. 16 rows x 3072 cols per block. Grid (192, P) = 768 blocks.
__global__ __launch_bounds__(256) void k2_e(const float* __restrict__ edge,
                                            float* __restrict__ e_out,
                                            float* __restrict__ ws) {
    int p = blockIdx.y;
    int row0 = blockIdx.x * 16;
    int tid = threadIdx.x;
    const float* Wh1 = ws + WH1_OFF;
    const float4* Wh2v = (const float4*)(ws + WH2_OFF);
    float4 wv[3];
#pragma unroll
    for (int c = 0; c < 3; ++c) wv[c] = Wh2v[c * 256 + tid];
    float colAcc[12];
#pragma unroll
    for (int i = 0; i < 12; ++i) colAcc[i] = 0.f;
    float racc16[16];
    __shared__ float rowpart[16][4];
    const size_t slice = (size_t)p * NN * NN;
    const float4* ein = (const float4*)(edge + slice + (size_t)row0 * NN);
    float4* eout = (float4*)(e_out + slice + (size_t)row0 * NN);
    // row stride = NN/4 = 768 float4
    float4 c0 = ein[tid], c1 = ein[256 + tid], c2 = ein[512 + tid];
#pragma unroll
    for (int r = 0; r < 16; ++r) {
        float4 n0, n1, n2;
        if (r < 15) {
            const float4* nx = ein + (size_t)(r + 1) * 768;
            n0 = nx[tid]; n1 = nx[256 + tid]; n2 = nx[512 + tid];
        }
        float w1 = Wh1[row0 + r];
        float4* eor = eout + (size_t)r * 768;
        float racc = 0.f;
        float4 ea, w, ev;
        float b;
        // c = 0
        ea = c0; w = wv[0];
        b = w1 + w.x; b = b > 0.f ? b : LEAK * b; ev.x = b * ea.x;
        b = w1 + w.y; b = b > 0.f ? b : LEAK * b; ev.y = b * ea.y;
        b = w1 + w.z; b = b > 0.f ? b : LEAK * b; ev.z = b * ea.z;
        b = w1 + w.w; b = b > 0.f ? b : LEAK * b; ev.w = b * ea.w;
        eor[tid] = ev;
        colAcc[0] += ev.x; colAcc[1] += ev.y; colAcc[2] += ev.z; colAcc[3] += ev.w;
        racc += (ev.x + ev.y) + (ev.z + ev.w);
        // c = 1
        ea = c1; w = wv[1];
        b = w1 + w.x; b = b > 0.f ? b : LEAK * b; ev.x = b * ea.x;
        b = w1 + w.y; b = b > 0.f ? b : LEAK * b; ev.y = b * ea.y;
        b = w1 + w.z; b = b > 0.f ? b : LEAK * b; ev.z = b * ea.z;
        b = w1 + w.w; b = b > 0.f ? b : LEAK * b; ev.w = b * ea.w;
        eor[256 + tid] = ev;
        colAcc[4] += ev.x; colAcc[5] += ev.y; colAcc[6] += ev.z; colAcc[7] += ev.w;
        racc += (ev.x + ev.y) + (ev.z + ev.w);
        // c = 2
        ea = c2; w = wv[2];
        b = w1 + w.x; b = b > 0.f ? b : LEAK * b; ev.x = b * ea.x;
        b = w1 + w.y; b = b > 0.f ? b : LEAK * b; ev.y = b * ea.y;
        b = w1 + w.z; b = b > 0.f ? b : LEAK * b; ev.z = b * ea.z;
        b = w1 + w.w; b = b > 0.f ? b : LEAK * b; ev.w = b * ea.w;
        eor[512 + tid] = ev;
        colAcc[8] += ev.x; colAcc[9] += ev.y; colAcc[10] += ev.z; colAcc[11] += ev.w;
        racc += (ev.x + ev.y) + (ev.z + ev.w);
        racc16[r] = racc;
        c0 = n0; c1 = n1; c2 = n2;
    }
    // deferred row reductions
#pragma unroll
    for (int r = 0; r < 16; ++r) {
        float racc = racc16[r];
#pragma unroll
        for (int off = 32; off > 0; off >>= 1) racc += __shfl_down(racc, off);
        if ((tid & 63) == 0) rowpart[r][tid >> 6] = racc;
    }
    __syncthreads();
    if (tid < 64) {
        float vv = rowpart[tid >> 2][tid & 3];
        vv += __shfl_down(vv, 2);
        vv += __shfl_down(vv, 1);
        if ((tid & 3) == 0) ws[RS_OFF + p * NN + row0 + (tid >> 2)] = vv;
    }
    float4* cp = (float4*)(ws + CP_OFF + (size_t)(p * KB2 + blockIdx.x) * NN);
#pragma unroll
    for (int c = 0; c < 3; ++c) {
        float4 cv;
        cv.x = colAcc[c * 4 + 0]; cv.y = colAcc[c * 4 + 1];
        cv.z = colAcc[c * 4 + 2]; cv.w = colAcc[c * 4 + 3];
        cp[c * 256 + tid] = cv;
    }
}

// K3a: reduce 192 col partials -> cs. Grid (48, P); 256 thr = 64 cols x 4 chunks.
__global__ __launch_bounds__(256) void k3a_red(float* __restrict__ ws) {
    int p = blockIdx.y;
    int col = blockIdx.x * 64 + (threadIdx.x & 63);
    int chunk = threadIdx.x >> 6;  // 0..3, 48 partials each
    const float* cp = ws + CP_OFF + (size_t)p * KB2 * NN + (size_t)chunk * 48 * NN + col;
    float s = 0.f;
#pragma unroll 8
    for (int b = 0; b < 48; ++b) s += cp[(size_t)b * NN];
    __shared__ float sred[4][64];
    sred[chunk][threadIdx.x & 63] = s;
    __syncthreads();
    if (threadIdx.x < 64) {
        float t = sred[0][threadIdx.x] + sred[1][threadIdx.x] +
                  sred[2][threadIdx.x] + sred[3][threadIdx.x];
        ws[CS_OFF + p * NN + col] = t;
    }
}

// K3b: per-p scalars. lamb = max(max rs, max cs); r = N*lamb - T.
// u_i = (lamb-rs_i)/(r*lamb); v_j = lamb-cs_j; att = e>0 ? e/lamb + u_i*v_j : e
__global__ __launch_bounds__(256) void k3b_scal(float* __restrict__ ws) {
    int p = blockIdx.x;
    int tid = threadIdx.x;
    const float* rs = ws + RS_OFF + p * NN;
    const float* cs = ws + CS_OFF + p * NN;
    float mx = -3.4e38f, sum = 0.f;
    for (int i = tid; i < NN; i += 256) {
        float rv = rs[i], cv = cs[i];
        mx = fmaxf(mx, fmaxf(rv, cv));
        sum += rv;
    }
#pragma unroll
    for (int off = 32; off > 0; off >>= 1) {
        mx = fmaxf(mx, __shfl_down(mx, off));
        sum += __shfl_down(sum, off);
    }
    __shared__ float smx[4], ssum[4];
    __shared__ float s_lamb, s_invlr;
    if ((tid & 63) == 0) { smx[tid >> 6] = mx; ssum[tid >> 6] = sum; }
    __syncthreads();
    if (tid == 0) {
        float lamb = fmaxf(fmaxf(smx[0], smx[1]), fmaxf(smx[2], smx[3]));
        float T = ssum[0] + ssum[1] + ssum[2] + ssum[3];
        float r = (float)NN * lamb - T;
        s_lamb = lamb;
        s_invlr = 1.f / (r * lamb);
        ws[SCAL_OFF + p] = 1.f / lamb;
    }
    __syncthreads();
    float lamb = s_lamb, invlr = s_invlr;
    for (int i = tid; i < NN; i += 256) {
        ws[U_OFF + p * NN + i] = (lamb - rs[i]) * invlr;
        ws[V_OFF + p * NN + i] = lamb - cs[i];
    }
}

// K4: partial h_prime = att(e[:, Kchunk]) @ Wh[Kchunk, :] via bf16 MFMA.
// 256-thread blocks, 32x64 C-tile, coalesced staging with transform-on-the-fly
// into XOR-swizzled LDS (conflict-free b128 frag reads), double-buffered LDS
// AND depth-2 global prefetch (two register sets RA/RB): each tile's loads are
// issued a full phase (MM+ST+barrier) before their vmcnt-wait in ST.
// Grid (96, P, KS) = 1536 blocks.
__global__ __launch_bounds__(256) void k4_mfma(const float* __restrict__ e_in,
                                               float* __restrict__ ws) {
    int p = blockIdx.y;
    int z = blockIdx.z;
    int row0 = blockIdx.x * 32;
    int tid = threadIdx.x;
    int lane = tid & 63, wid = tid >> 6;

    __shared__ unsigned short sA[2][32 * 64];  // bf16 A-tile, swizzled
    __shared__ unsigned short sB[2][64 * 64];  // bf16 B-tile (whT), swizzled

    const unsigned short* whT = (const unsigned short*)(ws + WHT_OFF);
    const float* u = ws + U_OFF + p * NN;
    const float* v = ws + V_OFF + p * NN;
    float invl = ws[SCAL_OFF + p];
    const float* eslice = e_in + (size_t)p * NN * NN;

    // staging roles
    const int ar = tid >> 3, acg = tid & 7;   // A: row 0..31, col-group (4 floats; halves at +0/+32)
    const int bfr = tid >> 2, bkg = tid & 3;  // B: f-row 0..63, k-group (8 shorts; second at +32)
    const float u_r = u[row0 + ar];
    const float* erow = eslice + (size_t)(row0 + ar) * NN;
    const unsigned short* wrow = whT + (size_t)bfr * NN;
    const int aswL = ((acg >> 1) ^ (ar & 7)) * 8 + (acg & 1) * 4;
    const int aswH = (((acg >> 1) + 4) ^ (ar & 7)) * 8 + (acg & 1) * 4;
    const int bswL = (bkg ^ (bfr & 7)) * 8;
    const int bswH = ((bkg + 4) ^ (bfr & 7)) * 8;

    // fragment roles
    const int mrow = lane & 15, kq = lane >> 4;
    const int rt = wid & 1, ft = (wid >> 1) * 2;  // row-tile, first f-tile
    const int arow = rt * 16 + mrow;
    const int sw = mrow & 7;

    floatx4 acc0, acc1;
#pragma unroll
    for (int i = 0; i < 4; ++i) { acc0[i] = 0.f; acc1[i] = 0.f; }

    struct LdRegs { float4 eL, eH, vL, vH; int4 bL, bH; };
    auto LD = [&](LdRegs& R, int k0) {
        const float4* ep = (const float4*)(erow + k0);
        R.eL = ep[acg]; R.eH = ep[acg + 8];
        const float4* vp = (const float4*)(v + k0);
        R.vL = vp[acg]; R.vH = vp[acg + 8];
        const int4* wp = (const int4*)(wrow + k0);
        R.bL = wp[bkg]; R.bH = wp[bkg + 4];
    };
    auto ST = [&](const LdRegs& R, int b) {
        float a0 = R.eL.x > 0.f ? fmaf(u_r, R.vL.x, R.eL.x * invl) : R.eL.x;
        float a1 = R.eL.y > 0.f ? fmaf(u_r, R.vL.y, R.eL.y * invl) : R.eL.y;
        float a2 = R.eL.z > 0.f ? fmaf(u_r, R.vL.z, R.eL.z * invl) : R.eL.z;
        float a3 = R.eL.w > 0.f ? fmaf(u_r, R.vL.w, R.eL.w * invl) : R.eL.w;
        float a4 = R.eH.x > 0.f ? fmaf(u_r, R.vH.x, R.eH.x * invl) : R.eH.x;
        float a5 = R.eH.y > 0.f ? fmaf(u_r, R.vH.y, R.eH.y * invl) : R.eH.y;
        float a6 = R.eH.z > 0.f ? fmaf(u_r, R.vH.z, R.eH.z * invl) : R.eH.z;
        float a7 = R.eH.w > 0.f ? fmaf(u_r, R.vH.w, R.eH.w * invl) : R.eH.w;
        int2 lo, hi;
        lo.x = (int)f2bf(a0) | ((int)f2bf(a1) << 16);
        lo.y = (int)f2bf(a2) | ((int)f2bf(a3) << 16);
        hi.x = (int)f2bf(a4) | ((int)f2bf(a5) << 16);
        hi.y = (int)f2bf(a6) | ((int)f2bf(a7) << 16);
        *(int2*)&sA[b][ar * 64 + aswL] = lo;
        *(int2*)&sA[b][ar * 64 + aswH] = hi;
        *(int4*)&sB[b][bfr * 64 + bswL] = R.bL;
        *(int4*)&sB[b][bfr * 64 + bswH] = R.bH;
    };
    auto MM = [&](int b) {
        short8 a0 = *(const short8*)&sA[b][arow * 64 + (kq ^ sw) * 8];
        short8 a1 = *(const short8*)&sA[b][arow * 64 + ((4 + kq) ^ sw) * 8];
        int f0 = (ft * 16 + mrow) * 64;
        int f1 = f0 + 16 * 64;
        short8 b00 = *(const short8*)&sB[b][f0 + (kq ^ sw) * 8];
        short8 b01 = *(const short8*)&sB[b][f0 + ((4 + kq) ^ sw) * 8];
        short8 b10 = *(const short8*)&sB[b][f1 + (kq ^ sw) * 8];
        short8 b11 = *(const short8*)&sB[b][f1 + ((4 + kq) ^ sw) * 8];
        acc0 = __builtin_amdgcn_mfma_f32_16x16x32_bf16(a0, b00, acc0, 0, 0, 0);
        acc0 = __builtin_amdgcn_mfma_f32_16x16x32_bf16(a1, b01, acc0, 0, 0, 0);
        acc1 = __builtin_amdgcn_mfma_f32_16x16x32_bf16(a0, b10, acc1, 0, 0, 0);
        acc1 = __builtin_amdgcn_mfma_f32_16x16x32_bf16(a1, b11, acc1, 0, 0, 0);
    };

    const int kbase = z * KCH;
    const int NSTEP = KCH / 64;  // 12 (even)
    LdRegs RA, RB;
    LD(RA, kbase);
    ST(RA, 0);
    LD(RB, kbase + 64);          // in flight across the barrier
    __syncthreads();
    for (int s = 0; s < NSTEP; s += 2) {
        MM(0);                                        // tile s
        ST(RB, 1);                                    // tile s+1 (loaded 1 phase ago)
        if (s + 2 < NSTEP) LD(RA, kbase + (s + 2) * 64);
        __syncthreads();
        MM(1);                                        // tile s+1
        if (s + 2 < NSTEP) {
            ST(RA, 0);                                // tile s+2
            if (s + 3 < NSTEP) LD(RB, kbase + (s + 3) * 64);
            __syncthreads();
        }
    }
    // D layout: col = lane&15, row = (lane>>4)*4 + reg  [m89-verified]
    float* part = ws + CP_OFF + (size_t)z * PNF + (size_t)p * NN * FF + (size_t)row0 * FF;
#pragma unroll
    for (int r = 0; r < 4; ++r) {
        int crow = rt * 16 + kq * 4 + r;
        part[crow * FF + ft * 16 + mrow] = acc0[r];
        part[crow * FF + (ft + 1) * 16 + mrow] = acc1[r];
    }
}

// K5: sum KS partials + elu -> out0[n, p*64+f]. Grid 3072 x 256.
__global__ __launch_bounds__(256) void k5_red(const float* __restrict__ ws,
                                              float* __restrict__ out0) {
    int i = blockIdx.x * 256 + threadIdx.x;  // over [p][n][f]
    const float* part = ws + CP_OFF;
    float s = part[i] + part[PNF + i] + part[2 * PNF + i] + part[3 * (size_t)PNF + i];
    s = s > 0.f ? s : (expf(s) - 1.0f);  // elu alpha=1
    int f = i & 63;
    int p = i / (NN * FF);
    int n = (i - p * NN * FF) >> 6;
    out0[(size_t)n * (PP * FF) + p * FF + f] = s;
}

extern "C" void kernel_launch(void* const* d_in, const int* in_sizes, int n_in,
                              void* d_out, int out_size, void* d_ws, size_t ws_size,
                              hipStream_t stream) {
    const float* h    = (const float*)d_in[0];
    const float* edge = (const float*)d_in[1];
    const float* W    = (const float*)d_in[2];
    const float* a    = (const float*)d_in[3];
    float* out0  = (float*)d_out;                // [N, P*F] elu output
    float* e_out = out0 + (size_t)NN * PP * FF;  // [P, N, N] e output
    float* ws = (float*)d_ws;

    k1_gemm<<<NN, 64, 0, stream>>>(h, W, a, ws);
    k2_e<<<dim3(NN / 16, PP), 256, 0, stream>>>(edge, e_out, ws);
    k3a_red<<<dim3(NN / 64, PP), 256, 0, stream>>>(ws);
    k3b_scal<<<PP, 256, 0, stream>>>(ws);
    k4_mfma<<<dim3(NN / 32, PP, KS), 256, 0, stream>>>(e_out, ws);
    k5_red<<<PNF / 256, 256, 0, stream>>>(ws, out0);
}